// Round 8
// baseline (304.307 us; speedup 1.0000x reference)
//
#include <hip/hip_runtime.h>
#include <stdint.h>

// ---------------------------------------------------------------------------
// MultiHeadedAttention (B=2,S=2048,D=1024,H=16,DK=64)
//   INPUTS fp32 (query,key,value,Wqkv,Wout) + int32 mask; OUTPUT fp32.
//   head (b,h) = contiguous 2048x64 block; y[b][s][h*64+dk]; out=y@Wout^T.
// R8:
//   * pre-convert all fp32 GEMM operands to bf16 (one elementwise pass) ->
//     halves GEMM operand bytes, deletes per-iter v_cvt chains.
//   * new gemm_lds: all-bf16, BK=64, global_load_lds 16B staging (m97 trick),
//     unpadded panel LDS layout (lane-contiguous async dests + 2-way-free
//     b128 frag reads).
//   * ws_size guard: fast path needs 61 MB; else R7 fallback kernels.
//   * attn unchanged from R7 (77.5 us).
// ---------------------------------------------------------------------------

typedef __bf16 bf16;
typedef __bf16 bf16x8 __attribute__((ext_vector_type(8)));
typedef __bf16 bf16x4 __attribute__((ext_vector_type(4)));
typedef float f32x4 __attribute__((ext_vector_type(4)));

#define MFMA16(a, b, c) __builtin_amdgcn_mfma_f32_16x16x32_bf16((a), (b), (c), 0, 0, 0)
#define EXP2(x) __builtin_amdgcn_exp2f(x)

static constexpr int BATCH = 2;
static constexpr int SEQ = 2048;
static constexpr int DIM = 1024;
static constexpr int DK = 64;
// q is pre-scaled by 1/sqrt(DK) * log2(e) in the QKV GEMM epilogue (z==0)
static constexpr float QSCALE = 0.125f * 1.44269504088896340736f;

// ---- async 16B global -> LDS copy (gfx950 global_load_lds dwordx4) --------
__device__ __forceinline__ void gld16(const bf16* g, bf16* l) {
  __builtin_amdgcn_global_load_lds((const __attribute__((address_space(1))) void*)g,
                                   (__attribute__((address_space(3))) void*)l, 16, 0, 0);
}

// ---- 8-element stripe load/convert helpers (fallback path) ----------------
template <typename T>
struct Stripe;
template <>
struct Stripe<bf16> {
  uint4 v;
};
template <>
struct Stripe<float> {
  float4 a, b;
};

__device__ inline Stripe<bf16> load_stripe(const bf16* p) {
  Stripe<bf16> s;
  s.v = *(const uint4*)p;
  return s;
}
__device__ inline Stripe<float> load_stripe(const float* p) {
  Stripe<float> s;
  s.a = *(const float4*)p;
  s.b = *(const float4*)(p + 4);
  return s;
}
__device__ inline void store_stripe(bf16* d, const Stripe<bf16>& s) { *(uint4*)d = s.v; }
__device__ inline void store_stripe(bf16* d, const Stripe<float>& s) {
  bf16x8 v;
  v[0] = (bf16)s.a.x;
  v[1] = (bf16)s.a.y;
  v[2] = (bf16)s.a.z;
  v[3] = (bf16)s.a.w;
  v[4] = (bf16)s.b.x;
  v[5] = (bf16)s.b.y;
  v[6] = (bf16)s.b.z;
  v[7] = (bf16)s.b.w;
  *(bf16x8*)d = v;
}

// ---------------- fp32 -> bf16 conversion (8 elems/thread) -----------------
// blockIdx.y selects among up to 3 (src,dst) pairs.
__global__ __launch_bounds__(256) void conv3_kernel(const float* __restrict__ x0,
                                                    const float* __restrict__ x1,
                                                    const float* __restrict__ x2,
                                                    bf16* __restrict__ d0,
                                                    bf16* __restrict__ d1,
                                                    bf16* __restrict__ d2) {
  const float* x = (blockIdx.y == 0) ? x0 : (blockIdx.y == 1) ? x1 : x2;
  bf16* d = (blockIdx.y == 0) ? d0 : (blockIdx.y == 1) ? d1 : d2;
  size_t i = ((size_t)blockIdx.x * 256 + threadIdx.x) * 8;
  float4 a = *(const float4*)(x + i);
  float4 b = *(const float4*)(x + i + 4);
  bf16x8 v;
  v[0] = (bf16)a.x;
  v[1] = (bf16)a.y;
  v[2] = (bf16)a.z;
  v[3] = (bf16)a.w;
  v[4] = (bf16)b.x;
  v[5] = (bf16)b.y;
  v[6] = (bf16)b.z;
  v[7] = (bf16)b.w;
  *(bf16x8*)(d + i) = v;
}

// ---------------- mask (int32 0/1) -> bitmask, 1 bit per element -----------
__global__ __launch_bounds__(256) void mask_bits_kernel(const int* __restrict__ mask,
                                                        unsigned long long* __restrict__ bits) {
  int idx = blockIdx.x * 256 + threadIdx.x;  // grid covers exactly B*S*S
  int m = mask[idx];
  unsigned long long bal = __ballot(m != 0);
  if ((threadIdx.x & 63) == 0) bits[idx >> 6] = bal;
}

// ---------------- FAST GEMM (all-bf16, global_load_lds staging) ------------
// C[4096,1024](TC) = A @ W^T. 128x128 tile, BK=64, 4 waves (2x2).
// LDS: unpadded panel layout — element (row,col) of the 128x64 tile lives at
// panel p=col/8, offset p*1024 + row*8 + col%8. Staging stripe s=j*256+tid:
// row = tid&127 (const), panel = j*2 + (tid>>7); LDS byte off = s*16 ->
// wave-uniform base + lane*16 (global_load_lds requirement). Frag reads:
// b128 at panel (ks*4+quad), banks 4*row%32 -> 2-way (free).
template <typename TC>
__global__ __launch_bounds__(256) void gemm_lds(const bf16* __restrict__ A0,
                                                const bf16* __restrict__ A1,
                                                const bf16* __restrict__ A2,
                                                const bf16* __restrict__ W,
                                                TC* __restrict__ C0,
                                                TC* __restrict__ C1,
                                                TC* __restrict__ C2,
                                                float scale0) {
  constexpr int K = 1024, N = 1024;
  __shared__ bf16 As[128 * 64];
  __shared__ bf16 Bs[128 * 64];

  const bf16* A = (blockIdx.z == 0) ? A0 : (blockIdx.z == 1) ? A1 : A2;
  TC* C = (blockIdx.z == 0) ? C0 : (blockIdx.z == 1) ? C1 : C2;
  const float sc = (blockIdx.z == 0) ? scale0 : 1.0f;

  const int tid = threadIdx.x;
  const int lane = tid & 63;
  const int wv = tid >> 6;
  const int wm = wv >> 1, wn = wv & 1;
  const int lrow = lane & 15, quad = lane >> 4;
  const int m0 = blockIdx.y * 128, n0 = blockIdx.x * 128;

  const int srow = tid & 127;     // staging row (const across j)
  const int hi = tid >> 7;        // 0/1: panel parity
  const bf16* ga = A + (size_t)(m0 + srow) * K;
  const bf16* gb = W + (size_t)(n0 + srow) * K;

  const f32x4 fz = {0.f, 0.f, 0.f, 0.f};
  f32x4 acc[4][4];
#pragma unroll
  for (int i = 0; i < 4; ++i)
#pragma unroll
    for (int j = 0; j < 4; ++j) acc[i][j] = fz;

  for (int k0 = 0; k0 < K; k0 += 64) {
    __syncthreads();  // prior iteration's LDS reads done
#pragma unroll
    for (int j = 0; j < 4; ++j) {
      const int panel = j * 2 + hi;
      const int soff = (j * 256 + tid) * 8;  // LDS elems (=16B stripes)
      gld16(ga + k0 + panel * 8, &As[soff]);
      gld16(gb + k0 + panel * 8, &Bs[soff]);
    }
    __syncthreads();  // barrier drains vmcnt -> LDS visible

#pragma unroll
    for (int ks = 0; ks < 2; ++ks) {
      bf16x8 af[4], bfm[4];
#pragma unroll
      for (int mt = 0; mt < 4; ++mt)
        af[mt] = *(const bf16x8*)(&As[(ks * 4 + quad) * 1024 + (wm * 64 + mt * 16 + lrow) * 8]);
#pragma unroll
      for (int nt = 0; nt < 4; ++nt)
        bfm[nt] = *(const bf16x8*)(&Bs[(ks * 4 + quad) * 1024 + (wn * 64 + nt * 16 + lrow) * 8]);
#pragma unroll
      for (int mt = 0; mt < 4; ++mt)
#pragma unroll
        for (int nt = 0; nt < 4; ++nt) acc[mt][nt] = MFMA16(af[mt], bfm[nt], acc[mt][nt]);
    }
  }

  // epilogue: C/D layout col=lane&15, row=quad*4+reg
#pragma unroll
  for (int mt = 0; mt < 4; ++mt) {
    const int gm = m0 + wm * 64 + mt * 16 + quad * 4;
#pragma unroll
    for (int nt = 0; nt < 4; ++nt) {
      const int gn = n0 + wn * 64 + nt * 16 + lrow;
#pragma unroll
      for (int r = 0; r < 4; ++r) C[(size_t)(gm + r) * N + gn] = (TC)(acc[mt][nt][r] * sc);
    }
  }
}

// ---------------- FALLBACK GEMM (R7): mixed-dtype staging ------------------
template <int BM, typename TA, typename TW, typename TC>
__global__ __launch_bounds__(256, 2) void gemm_bt(const TA* __restrict__ A0,
                                                  const TA* __restrict__ A1,
                                                  const TA* __restrict__ A2,
                                                  const TW* __restrict__ W,
                                                  TC* __restrict__ C0,
                                                  TC* __restrict__ C1,
                                                  TC* __restrict__ C2,
                                                  float scale0) {
  constexpr int K = 1024, N = 1024, LDA = 40;
  constexpr int MT = BM / 32;
  __shared__ bf16 As[BM * LDA];
  __shared__ bf16 Bs[128 * LDA];

  const TA* A = (blockIdx.z == 0) ? A0 : (blockIdx.z == 1) ? A1 : A2;
  TC* C = (blockIdx.z == 0) ? C0 : (blockIdx.z == 1) ? C1 : C2;
  const float sc = (blockIdx.z == 0) ? scale0 : 1.0f;

  const int tid = threadIdx.x;
  const int lane = tid & 63;
  const int wv = tid >> 6;
  const int wm = wv >> 1, wn = wv & 1;
  const int lrow = lane & 15, quad = lane >> 4;
  const int m0 = blockIdx.y * BM, n0 = blockIdx.x * 128;

  const f32x4 fz = {0.f, 0.f, 0.f, 0.f};
  f32x4 acc[MT][4];
#pragma unroll
  for (int i = 0; i < MT; ++i)
#pragma unroll
    for (int j = 0; j < 4; ++j) acc[i][j] = fz;

  const int r0 = tid >> 2;
  const int c0 = (tid & 3) * 8;
  const TA* pa0 = A + (size_t)(m0 + r0) * K + c0;
  const TA* pa1 = pa0;
  const TW* pb0 = W + (size_t)(n0 + r0) * K + c0;
  const TW* pb1 = W + (size_t)(n0 + r0 + 64) * K + c0;
  bf16* wa0 = &As[r0 * LDA + c0];
  bf16* wa1 = &As[((r0 + 64) & (2 * BM - 1)) * LDA + c0];
  bf16* wb0 = &Bs[r0 * LDA + c0];
  bf16* wb1 = &Bs[(r0 + 64) * LDA + c0];
  if constexpr (BM == 128) pa1 = A + (size_t)(m0 + r0 + 64) * K + c0;

  Stripe<TA> ra0 = load_stripe(pa0);
  Stripe<TA> ra1;
  if constexpr (BM == 128) ra1 = load_stripe(pa1);
  Stripe<TW> rb0 = load_stripe(pb0);
  Stripe<TW> rb1 = load_stripe(pb1);

  for (int k0 = 0; k0 < K; k0 += 32) {
    __syncthreads();
    store_stripe(wa0, ra0);
    if constexpr (BM == 128) store_stripe(wa1, ra1);
    store_stripe(wb0, rb0);
    store_stripe(wb1, rb1);
    __syncthreads();
    if (k0 + 32 < K) {
      ra0 = load_stripe(pa0 + k0 + 32);
      if constexpr (BM == 128) ra1 = load_stripe(pa1 + k0 + 32);
      rb0 = load_stripe(pb0 + k0 + 32);
      rb1 = load_stripe(pb1 + k0 + 32);
    }
    bf16x8 af[MT], bfr[4];
#pragma unroll
    for (int mt = 0; mt < MT; ++mt)
      af[mt] = *(const bf16x8*)(&As[(wm * (BM / 2) + mt * 16 + lrow) * LDA + quad * 8]);
#pragma unroll
    for (int nt = 0; nt < 4; ++nt)
      bfr[nt] = *(const bf16x8*)(&Bs[(wn * 64 + nt * 16 + lrow) * LDA + quad * 8]);
#pragma unroll
    for (int mt = 0; mt < MT; ++mt)
#pragma unroll
      for (int nt = 0; nt < 4; ++nt) acc[mt][nt] = MFMA16(af[mt], bfr[nt], acc[mt][nt]);
  }

#pragma unroll
  for (int mt = 0; mt < MT; ++mt) {
    const int gm = m0 + wm * (BM / 2) + mt * 16 + quad * 4;
#pragma unroll
    for (int nt = 0; nt < 4; ++nt) {
      const int gn = n0 + wn * 64 + nt * 16 + lrow;
#pragma unroll
      for (int r = 0; r < 4; ++r) C[(size_t)(gm + r) * N + gn] = (TC)(acc[mt][nt][r] * sc);
    }
  }
}

// ---------------- flash attention, transposed-S form (R7, unchanged) --------
__global__ __launch_bounds__(256, 2) void attn_kernel(const bf16* __restrict__ Qg,
                                                      const bf16* __restrict__ Kg,
                                                      const bf16* __restrict__ Vg,
                                                      const unsigned* __restrict__ bits,
                                                      bf16* __restrict__ Y) {
  constexpr int LQ = 72;
  __shared__ bf16 Qs[128 * LQ];  // after qf extraction: K/V buffer 1
  __shared__ bf16 Ks[64 * LQ];
  __shared__ bf16 Vts[64 * LQ];
  __shared__ bf16 Ps[4][32 * LQ];

  const int tid = threadIdx.x;
  const int lane = tid & 63;
  const int wv = tid >> 6;
  const int lrow = lane & 15, quad = lane >> 4;
  const int bh = blockIdx.y;
  const int b = bh >> 4, h = bh & 15;
  const int q0 = blockIdx.x * 128;

  const bf16* Qh = Qg + (size_t)bh * (SEQ * DK);
  const bf16* Kh = Kg + (size_t)bh * (SEQ * DK);
  const bf16* Vh = Vg + (size_t)bh * (SEQ * DK);

#pragma unroll
  for (int i = 0; i < 4; ++i) {
    int s = tid + i * 256;
    int row = s >> 3, c8 = (s & 7) * 8;
    *(uint4*)(&Qs[row * LQ + c8]) = *(const uint4*)(Qh + (size_t)(q0 + row) * DK + c8);
  }

  const int krow = tid >> 3;
  const int kc8 = (tid & 7) * 8;
  const bf16* pk0 = Kh + (size_t)krow * DK + kc8;
  const bf16* pk1 = Kh + (size_t)(krow + 32) * DK + kc8;
  const int vn2 = tid & 31;
  const int vk2b = tid >> 5;
  const bf16* pv0 = Vh + (size_t)(vk2b + 0) * 2 * DK + vn2 * 2;
  const bf16* pv1 = Vh + (size_t)(vk2b + 8) * 2 * DK + vn2 * 2;
  const bf16* pv2 = Vh + (size_t)(vk2b + 16) * 2 * DK + vn2 * 2;
  const bf16* pv3 = Vh + (size_t)(vk2b + 24) * 2 * DK + vn2 * 2;

  uint4 kr0, kr1;
  uint32_t va[4], vb[4];

  kr0 = *(const uint4*)(pk0);
  kr1 = *(const uint4*)(pk1);
  va[0] = *(const uint32_t*)(pv0);
  vb[0] = *(const uint32_t*)(pv0 + DK);
  va[1] = *(const uint32_t*)(pv1);
  vb[1] = *(const uint32_t*)(pv1 + DK);
  va[2] = *(const uint32_t*)(pv2);
  vb[2] = *(const uint32_t*)(pv2 + DK);
  va[3] = *(const uint32_t*)(pv3);
  vb[3] = *(const uint32_t*)(pv3 + DK);
  *(uint4*)(&Ks[krow * LQ + kc8]) = kr0;
  *(uint4*)(&Ks[(krow + 32) * LQ + kc8]) = kr1;
#pragma unroll
  for (int i = 0; i < 4; ++i) {
    uint32_t t0 = (va[i] & 0xffffu) | (vb[i] << 16);
    uint32_t t1 = (va[i] >> 16) | (vb[i] & 0xffff0000u);
    *(uint32_t*)(&Vts[(vn2 * 2) * LQ + (vk2b + i * 8) * 2]) = t0;
    *(uint32_t*)(&Vts[(vn2 * 2 + 1) * LQ + (vk2b + i * 8) * 2]) = t1;
  }
  __syncthreads();

  bf16x8 qf[2][2];
#pragma unroll
  for (int nt = 0; nt < 2; ++nt)
#pragma unroll
    for (int ks = 0; ks < 2; ++ks)
      qf[nt][ks] = *(const bf16x8*)(&Qs[(wv * 32 + nt * 16 + lrow) * LQ + ks * 32 + quad * 8]);
  __syncthreads();

  const f32x4 fz = {0.f, 0.f, 0.f, 0.f};
  f32x4 of_t[4][2];
#pragma unroll
  for (int i = 0; i < 4; ++i)
#pragma unroll
    for (int j = 0; j < 2; ++j) of_t[i][j] = fz;
  float lsum[2] = {0.f, 0.f};

  const unsigned* bitrow = bits + (size_t)b * SEQ * (SEQ / 32);

  for (int kt = 0; kt < 32; ++kt) {
    const int cur = kt & 1;
    bf16* kb = cur ? Qs : Ks;
    bf16* vbuf = cur ? (Qs + 64 * LQ) : Vts;
    if (kt + 1 < 32) {
      const size_t adv = (size_t)(kt + 1) * 64 * DK;
      kr0 = *(const uint4*)(pk0 + adv);
      kr1 = *(const uint4*)(pk1 + adv);
      va[0] = *(const uint32_t*)(pv0 + adv);
      vb[0] = *(const uint32_t*)(pv0 + adv + DK);
      va[1] = *(const uint32_t*)(pv1 + adv);
      vb[1] = *(const uint32_t*)(pv1 + adv + DK);
      va[2] = *(const uint32_t*)(pv2 + adv);
      vb[2] = *(const uint32_t*)(pv2 + adv + DK);
      va[3] = *(const uint32_t*)(pv3 + adv);
      vb[3] = *(const uint32_t*)(pv3 + adv + DK);
    }
    uint2 mwn[2];
#pragma unroll
    for (int nt = 0; nt < 2; ++nt) {
      int row = q0 + wv * 32 + nt * 16 + lrow;
      mwn[nt] = *(const uint2*)(bitrow + (size_t)row * (SEQ / 32) + kt * 2);
    }

    f32x4 st[4][2];
#pragma unroll
    for (int mt = 0; mt < 4; ++mt)
#pragma unroll
      for (int nt = 0; nt < 2; ++nt) st[mt][nt] = fz;
#pragma unroll
    for (int ks = 0; ks < 2; ++ks) {
#pragma unroll
      for (int mt = 0; mt < 4; ++mt) {
        bf16x8 kfv = *(const bf16x8*)(kb + (mt * 16 + lrow) * LQ + ks * 32 + quad * 8);
#pragma unroll
        for (int nt = 0; nt < 2; ++nt) st[mt][nt] = MFMA16(kfv, qf[nt][ks], st[mt][nt]);
      }
    }

#pragma unroll
    for (int nt = 0; nt < 2; ++nt) {
      uint32_t ux = mwn[nt].x >> (quad * 4);
      uint32_t uy = mwn[nt].y >> (quad * 4);
      float psum = 0.f;
#pragma unroll
      for (int mt = 0; mt < 4; ++mt) {
        uint32_t u = (mt & 2) ? uy : ux;
        int sh = (mt & 1) << 4;
        bf16x4 pk;
#pragma unroll
        for (int r = 0; r < 4; ++r) {
          float p = EXP2(st[mt][nt][r]);
          p = ((u >> (sh + r)) & 1u) ? p : 0.f;
          psum += p;
          pk[r] = (bf16)p;
        }
        *(bf16x4*)(&Ps[wv][(nt * 16 + lrow) * LQ + mt * 16 + quad * 4]) = pk;
      }
      lsum[nt] += psum;
    }

#pragma unroll
    for (int ks = 0; ks < 2; ++ks) {
      bf16x8 avf[4], bpf[2];
#pragma unroll
      for (int dkt = 0; dkt < 4; ++dkt)
        avf[dkt] = *(const bf16x8*)(vbuf + (dkt * 16 + lrow) * LQ + ks * 32 + quad * 8);
#pragma unroll
      for (int rt = 0; rt < 2; ++rt)
        bpf[rt] = *(const bf16x8*)(&Ps[wv][(rt * 16 + lrow) * LQ + ks * 32 + quad * 8]);
#pragma unroll
      for (int dkt = 0; dkt < 4; ++dkt)
#pragma unroll
        for (int rt = 0; rt < 2; ++rt) of_t[dkt][rt] = MFMA16(avf[dkt], bpf[rt], of_t[dkt][rt]);
    }

    if (kt + 1 < 32) {
      bf16* kbn = cur ? Ks : Qs;
      bf16* vbn = cur ? Vts : (Qs + 64 * LQ);
      *(uint4*)(kbn + krow * LQ + kc8) = kr0;
      *(uint4*)(kbn + (krow + 32) * LQ + kc8) = kr1;
#pragma unroll
      for (int i = 0; i < 4; ++i) {
        uint32_t t0 = (va[i] & 0xffffu) | (vb[i] << 16);
        uint32_t t1 = (va[i] >> 16) | (vb[i] & 0xffff0000u);
        *(uint32_t*)(vbn + (vn2 * 2) * LQ + (vk2b + i * 8) * 2) = t0;
        *(uint32_t*)(vbn + (vn2 * 2 + 1) * LQ + (vk2b + i * 8) * 2) = t1;
      }
    }
    __syncthreads();
  }

  float linv[2];
#pragma unroll
  for (int nt = 0; nt < 2; ++nt) {
    float v = lsum[nt];
    v += __shfl_xor(v, 16);
    v += __shfl_xor(v, 32);
    linv[nt] = 1.0f / fmaxf(v, 1e-20f);
  }

#pragma unroll
  for (int dkt = 0; dkt < 4; ++dkt)
#pragma unroll
    for (int rt = 0; rt < 2; ++rt) {
      bf16x4 o;
#pragma unroll
      for (int j = 0; j < 4; ++j) o[j] = (bf16)(of_t[dkt][rt][j] * linv[rt]);
      const int row = q0 + wv * 32 + rt * 16 + lrow;
      *(bf16x4*)(&Y[((size_t)b * SEQ + row) * DIM + h * 64 + dkt * 16 + quad * 4]) = o;
    }
}

// ---------------------------------------------------------------------------
extern "C" void kernel_launch(void* const* d_in, const int* in_sizes, int n_in,
                              void* d_out, int out_size, void* d_ws, size_t ws_size,
                              hipStream_t stream) {
  const float* query = (const float*)d_in[0];
  const float* key = (const float*)d_in[1];
  const float* value = (const float*)d_in[2];
  const float* Wqkv = (const float*)d_in[3];
  const float* Wout = (const float*)d_in[4];
  const int* mask = (const int*)d_in[5];
  float* out = (float*)d_out;

  char* ws = (char*)d_ws;
  constexpr size_t MB = 1048576;
  bf16* q = (bf16*)(ws);             //  8 MB (pre-scaled by QSCALE)
  bf16* k = (bf16*)(ws + 8 * MB);    //  8 MB
  bf16* v = (bf16*)(ws + 16 * MB);   //  8 MB
  bf16* y = (bf16*)(ws + 24 * MB);   //  8 MB
  unsigned long long* bits64 = (unsigned long long*)(ws + 32 * MB);  // 1 MB

  // 1) mask -> bits
  mask_bits_kernel<<<(BATCH * SEQ * SEQ) / 256, 256, 0, stream>>>(mask, bits64);

  if (ws_size >= 61 * MB) {
    // ---- fast path: bf16 operand pre-conversion + global_load_lds GEMM ----
    bf16* qb = (bf16*)(ws + 33 * MB);   // 8 MB
    bf16* kb = (bf16*)(ws + 41 * MB);   // 8 MB
    bf16* vb = (bf16*)(ws + 49 * MB);   // 8 MB
    bf16* Wqb = (bf16*)(ws + 57 * MB);  // 2 MB
    bf16* Wob = (bf16*)(ws + 59 * MB);  // 2 MB

    // activations: 3 x 4.19M elems; weights: 2 x 1.05M elems
    conv3_kernel<<<dim3(2048, 3), 256, 0, stream>>>(query, key, value, qb, kb, vb);
    conv3_kernel<<<dim3(512, 2), 256, 0, stream>>>(Wqkv, Wout, Wout, Wqb, Wob, Wob);

    // QKV projection (q scaled by QSCALE in epilogue, z==0 only)
    gemm_lds<bf16><<<dim3(8, 32, 3), 256, 0, stream>>>(qb, kb, vb, Wqb, q, k, v, QSCALE);

    // flash attention
    attn_kernel<<<dim3(16, 32), 256, 0, stream>>>(q, k, v, (const unsigned*)bits64, y);

    // output projection -> fp32 out
    gemm_lds<float><<<dim3(8, 32, 1), 256, 0, stream>>>(y, y, y, Wob, out, out, out, 1.0f);
  } else {
    // ---- fallback: R7 path (fp32 staging GEMMs) ----
    gemm_bt<128, float, float, bf16>
        <<<dim3(8, 32, 3), 256, 0, stream>>>(query, key, value, Wqkv, q, k, v, QSCALE);
    attn_kernel<<<dim3(16, 32), 256, 0, stream>>>(q, k, v, (const unsigned*)bits64, y);
    gemm_bt<64, bf16, float, float>
        <<<dim3(8, 64, 1), 256, 0, stream>>>(y, y, y, Wout, out, out, out, 1.0f);
  }
}